// Round 5
// baseline (929.069 us; speedup 1.0000x reference)
//
#include <hip/hip_runtime.h>
#include <math.h>

#define N_NODES 100000
#define N_EDGES 1600000
#define NBUCK 391          // ceil(100000 / 256)

typedef __attribute__((ext_vector_type(8))) _Float16 h8v;
typedef __attribute__((ext_vector_type(4))) float f32x4;
typedef __attribute__((ext_vector_type(2))) _Float16 h2v;

// ---------------- CSR build (bucketed, packed) ----------------

__global__ void k_zero_int(int* __restrict__ p, int n) {
    int i = blockIdx.x * blockDim.x + threadIdx.x;
    if (i < n) p[i] = 0;
}

__launch_bounds__(256)
__global__ void k_bhist(const int* __restrict__ dstv, int* __restrict__ bcnt) {
    __shared__ int hist[NBUCK];
    const int tid = threadIdx.x;
    for (int t = tid; t < NBUCK; t += 256) hist[t] = 0;
    __syncthreads();
    const int base = blockIdx.x * 4096;
#pragma unroll
    for (int i = 0; i < 16; i++) {
        int e = base + i * 256 + tid;
        if (e < N_EDGES) atomicAdd(&hist[dstv[e] >> 8], 1);
    }
    __syncthreads();
    for (int t = tid; t < NBUCK; t += 256)
        if (hist[t]) atomicAdd(&bcnt[t], hist[t]);
}

__global__ void k_bscan(const int* __restrict__ bcnt, int* __restrict__ bptr,
                        int* __restrict__ bcur) {
    __shared__ int s[512];
    int tid = threadIdx.x;
    int v = (tid < NBUCK) ? bcnt[tid] : 0;
    int x = v;
    s[tid] = x;
    __syncthreads();
    for (int d = 1; d < 512; d <<= 1) {
        int t = (tid >= d) ? s[tid - d] : 0;
        __syncthreads();
        x += t;
        s[tid] = x;
        __syncthreads();
    }
    if (tid < NBUCK) {
        bptr[tid] = x - v;
        bcur[tid] = x - v;
    }
    if (tid == NBUCK - 1) bptr[NBUCK] = x;
}

__launch_bounds__(256)
__global__ void k_bpart(const int* __restrict__ srcv, const int* __restrict__ dstv,
                        int* __restrict__ bcur, unsigned int* __restrict__ ebuf) {
    __shared__ int hist[NBUCK];
    __shared__ int cur[NBUCK];
    const int tid = threadIdx.x;
    for (int t = tid; t < NBUCK; t += 256) hist[t] = 0;
    __syncthreads();
    const int base = blockIdx.x * 4096;
#pragma unroll
    for (int i = 0; i < 16; i++) {
        int e = base + i * 256 + tid;
        if (e < N_EDGES) atomicAdd(&hist[dstv[e] >> 8], 1);
    }
    __syncthreads();
    for (int t = tid; t < NBUCK; t += 256)
        cur[t] = hist[t] ? atomicAdd(&bcur[t], hist[t]) : 0;
    __syncthreads();
#pragma unroll
    for (int i = 0; i < 16; i++) {
        int e = base + i * 256 + tid;
        if (e < N_EDGES) {
            int d = dstv[e];
            int p = atomicAdd(&cur[d >> 8], 1);
            ebuf[p] = ((unsigned int)srcv[e] << 8) | (unsigned int)(d & 255);
        }
    }
}

__launch_bounds__(256)
__global__ void k_brow(const unsigned int* __restrict__ ebuf, const int* __restrict__ bptr,
                       int* __restrict__ rowptr, float* __restrict__ dinv) {
    __shared__ int cnt[256];
    __shared__ int s[256];
    const int tid = threadIdx.x;
    cnt[tid] = 0;
    __syncthreads();
    const int b = blockIdx.x;
    const int e0 = bptr[b], e1 = bptr[b + 1];
    for (int e = e0 + tid; e < e1; e += 256) atomicAdd(&cnt[ebuf[e] & 255u], 1);
    __syncthreads();
    int v = cnt[tid];
    int x = v;
    s[tid] = x;
    __syncthreads();
    for (int d = 1; d < 256; d <<= 1) {
        int t = (tid >= d) ? s[tid - d] : 0;
        __syncthreads();
        x += t;
        s[tid] = x;
        __syncthreads();
    }
    int node = b * 256 + tid;
    if (node < N_NODES) {
        rowptr[node] = e0 + x - v;
        dinv[node] = rsqrtf((float)(v + 1));  // +1 self-loop
        if (node == N_NODES - 1) rowptr[N_NODES] = N_EDGES;
    }
}

__launch_bounds__(256)
__global__ void k_bfill(const unsigned int* __restrict__ ebuf, const int* __restrict__ bptr,
                        const int* __restrict__ rowptr, int* __restrict__ colidx) {
    __shared__ int cur[256];
    const int tid = threadIdx.x;
    const int b = blockIdx.x;
    int node = b * 256 + tid;
    cur[tid] = (node < N_NODES) ? rowptr[node] : 0;
    __syncthreads();
    const int e0 = bptr[b], e1 = bptr[b + 1];
    for (int e = e0 + tid; e < e1; e += 256) {
        unsigned int sd = ebuf[e];
        int pos = atomicAdd(&cur[sd & 255u], 1);
        colidx[pos] = (int)(sd >> 8);
    }
}

// ---------------- weight conversion ----------------

__global__ void k_wprep(const float* __restrict__ W, int ncols, int ntcols,
                        _Float16* __restrict__ Wthi, _Float16* __restrict__ Wtlo) {
    int idx = blockIdx.x * blockDim.x + threadIdx.x;
    if (idx >= ntcols * 128) return;
    int n = idx / 128, k = idx % 128;
    float v = (n < ncols) ? W[k * ncols + n] : 0.f;
    _Float16 hi = (_Float16)v;
    _Float16 lo = (_Float16)(v - (float)hi);
    Wthi[n * 128 + k] = hi;
    Wtlo[n * 128 + k] = lo;
}

// ---------------- MFMA GEMMs (W = Whi+Wlo split f16) ----------------
// Output layout is CHUNK-MAJOR: out[chunk][node][16], chunk = col/16.

// Layer-1 variant: A is fp32 (raw x), converted in-register.
__launch_bounds__(256)
__global__ void k_gemm128_f32(const float* __restrict__ Af,
                              const _Float16* __restrict__ Wthi, const _Float16* __restrict__ Wtlo,
                              const float* __restrict__ dinv, _Float16* __restrict__ out) {
    const int lane = threadIdx.x & 63;
    const int wi = threadIdx.x >> 6;
    const int r0 = blockIdx.x * 32;
    const int nb = wi * 32;
    const int nn = lane & 15;
    const int kq = (lane >> 4) * 8;

    h8v bh[4][2], bl[4][2];
#pragma unroll
    for (int c = 0; c < 4; c++)
#pragma unroll
        for (int t = 0; t < 2; t++) {
            int off = (nb + t * 16 + nn) * 128 + c * 32 + kq;
            bh[c][t] = *(const h8v*)(Wthi + off);
            bl[c][t] = *(const h8v*)(Wtlo + off);
        }

    f32x4 acc[2][2] = {};
#pragma unroll
    for (int c = 0; c < 4; c++) {
        h8v a[2];
#pragma unroll
        for (int m = 0; m < 2; m++) {
            const float* p = Af + (size_t)(r0 + m * 16 + nn) * 128 + c * 32 + kq;
            float4 p0 = *(const float4*)p;
            float4 p1 = *(const float4*)(p + 4);
            h8v av = {(_Float16)p0.x, (_Float16)p0.y, (_Float16)p0.z, (_Float16)p0.w,
                      (_Float16)p1.x, (_Float16)p1.y, (_Float16)p1.z, (_Float16)p1.w};
            a[m] = av;
        }
#pragma unroll
        for (int m = 0; m < 2; m++)
#pragma unroll
            for (int t = 0; t < 2; t++) {
                acc[m][t] = __builtin_amdgcn_mfma_f32_16x16x32_f16(a[m], bh[c][t], acc[m][t], 0, 0, 0);
                acc[m][t] = __builtin_amdgcn_mfma_f32_16x16x32_f16(a[m], bl[c][t], acc[m][t], 0, 0, 0);
            }
    }

    const int quad = lane >> 4;
#pragma unroll
    for (int m = 0; m < 2; m++) {
#pragma unroll
        for (int reg = 0; reg < 4; reg++) {
            int r = r0 + m * 16 + quad * 4 + reg;
            float dv = dinv[r];
#pragma unroll
            for (int t = 0; t < 2; t++)
                out[(size_t)(wi * 2 + t) * (N_NODES * 16) + (size_t)r * 16 + nn] =
                    (_Float16)(acc[m][t][reg] * dv);
        }
    }
}

__launch_bounds__(256)
__global__ void k_gemm128(const _Float16* __restrict__ A,
                          const _Float16* __restrict__ Wthi, const _Float16* __restrict__ Wtlo,
                          const float* __restrict__ dinv, _Float16* __restrict__ out) {
    const int lane = threadIdx.x & 63;
    const int wi = threadIdx.x >> 6;
    const int r0 = blockIdx.x * 32;
    const int nb = wi * 32;
    const int nn = lane & 15;
    const int kq = (lane >> 4) * 8;

    h8v bh[4][2], bl[4][2];
#pragma unroll
    for (int c = 0; c < 4; c++)
#pragma unroll
        for (int t = 0; t < 2; t++) {
            int off = (nb + t * 16 + nn) * 128 + c * 32 + kq;
            bh[c][t] = *(const h8v*)(Wthi + off);
            bl[c][t] = *(const h8v*)(Wtlo + off);
        }

    f32x4 acc[2][2] = {};
#pragma unroll
    for (int c = 0; c < 4; c++) {
        h8v a[2];
#pragma unroll
        for (int m = 0; m < 2; m++)
            a[m] = *(const h8v*)(A + (size_t)(r0 + m * 16 + nn) * 128 + c * 32 + kq);
#pragma unroll
        for (int m = 0; m < 2; m++)
#pragma unroll
            for (int t = 0; t < 2; t++) {
                acc[m][t] = __builtin_amdgcn_mfma_f32_16x16x32_f16(a[m], bh[c][t], acc[m][t], 0, 0, 0);
                acc[m][t] = __builtin_amdgcn_mfma_f32_16x16x32_f16(a[m], bl[c][t], acc[m][t], 0, 0, 0);
            }
    }

    const int quad = lane >> 4;
#pragma unroll
    for (int m = 0; m < 2; m++) {
#pragma unroll
        for (int reg = 0; reg < 4; reg++) {
            int r = r0 + m * 16 + quad * 4 + reg;
            float dv = dinv[r];
#pragma unroll
            for (int t = 0; t < 2; t++)
                out[(size_t)(wi * 2 + t) * (N_NODES * 16) + (size_t)r * 16 + nn] =
                    (_Float16)(acc[m][t][reg] * dv);
        }
    }
}

// NC=40 padded to 48 -> 3 chunks. Wave owns its own 32-row strip, all cols.
__launch_bounds__(256)
__global__ void k_gemm40(const _Float16* __restrict__ A,
                         const _Float16* __restrict__ Wthi, const _Float16* __restrict__ Wtlo,
                         const float* __restrict__ dinv, _Float16* __restrict__ out) {
    const int lane = threadIdx.x & 63;
    const int wi = threadIdx.x >> 6;
    const int r0 = (blockIdx.x * 4 + wi) * 32;
    const int nn = lane & 15;
    const int kq = (lane >> 4) * 8;

    h8v bh[4][3], bl[4][3];
#pragma unroll
    for (int c = 0; c < 4; c++)
#pragma unroll
        for (int t = 0; t < 3; t++) {
            int off = (t * 16 + nn) * 128 + c * 32 + kq;
            bh[c][t] = *(const h8v*)(Wthi + off);
            bl[c][t] = *(const h8v*)(Wtlo + off);
        }

    f32x4 acc[2][3] = {};
#pragma unroll
    for (int c = 0; c < 4; c++) {
        h8v a[2];
#pragma unroll
        for (int m = 0; m < 2; m++) {
            int rr = min(r0 + m * 16 + nn, N_NODES - 1);
            a[m] = *(const h8v*)(A + (size_t)rr * 128 + c * 32 + kq);
        }
#pragma unroll
        for (int m = 0; m < 2; m++)
#pragma unroll
            for (int t = 0; t < 3; t++) {
                acc[m][t] = __builtin_amdgcn_mfma_f32_16x16x32_f16(a[m], bh[c][t], acc[m][t], 0, 0, 0);
                acc[m][t] = __builtin_amdgcn_mfma_f32_16x16x32_f16(a[m], bl[c][t], acc[m][t], 0, 0, 0);
            }
    }

    const int quad = lane >> 4;
#pragma unroll
    for (int m = 0; m < 2; m++) {
#pragma unroll
        for (int reg = 0; reg < 4; reg++) {
            int r = r0 + m * 16 + quad * 4 + reg;
            if (r < N_NODES) {
                float dv = dinv[r];
#pragma unroll
                for (int t = 0; t < 3; t++)
                    out[(size_t)t * (N_NODES * 16) + (size_t)r * 16 + nn] =
                        (_Float16)(acc[m][t][reg] * dv);
            }
        }
    }
}

// ---------------- Chunked aggregation ----------------
// hpc: [NCHUNK][N][16] fp16 (one 3.2MB slice per chunk -> L2-resident per pass).
// grid.x covers rows (64/block), grid.y = chunk. Wave layout: 8 edges x 8 col-pairs.
// Output row-major [N][OUTSTRIDE] fp16 at col base chunk*16.

template <int OUTSTRIDE, bool RELU, bool BIAS>
__launch_bounds__(256)
__global__ void k_agg_chunk(const _Float16* __restrict__ hpc, const int* __restrict__ rowptr,
                            const int* __restrict__ colidx, const float* __restrict__ dinv,
                            const float* __restrict__ bias, _Float16* __restrict__ outp) {
    const int lane = threadIdx.x & 63;
    const int wave = threadIdx.x >> 6;
    const int chunk = blockIdx.y;
    const h2v* hp2 = (const h2v*)(hpc + (size_t)chunk * (N_NODES * 16));
    const int esub = lane >> 3;  // edge sub-index 0..7
    const int cp = lane & 7;     // col pair 0..7

    const int rbase = blockIdx.x * 64 + wave * 16;
    for (int i = 0; i < 16; i++) {
        int r = rbase + i;
        if (r >= N_NODES) return;
        const int e0 = rowptr[r], e1 = rowptr[r + 1];
        float ax = 0.f, ay = 0.f;
        for (int e = e0; e < e1; e += 8) {
            int idx = e + esub;
            if (idx < e1) {
                int s = colidx[idx];
                h2v v = hp2[(size_t)s * 8 + cp];
                ax += (float)v.x;
                ay += (float)v.y;
            }
        }
#pragma unroll
        for (int off = 8; off < 64; off <<= 1) {
            ax += __shfl_xor(ax, off);
            ay += __shfl_xor(ay, off);
        }
        if (lane < 8) {
            h2v sv = hp2[(size_t)r * 8 + cp];  // self-loop term
            ax += (float)sv.x;
            ay += (float)sv.y;
            float dv = dinv[r];
            float bx = 0.f, by = 0.f;
            if (BIAS) {
                float2 b = ((const float2*)bias)[chunk * 8 + cp];
                bx = b.x; by = b.y;
            }
            float ox = fmaf(dv, ax, bx);
            float oy = fmaf(dv, ay, by);
            if (RELU) { ox = fmaxf(ox, 0.f); oy = fmaxf(oy, 0.f); }
            h2v o = {(_Float16)ox, (_Float16)oy};
            *(h2v*)(outp + (size_t)r * OUTSTRIDE + chunk * 16 + cp * 2) = o;
        }
    }
}

// ---------------- log_softmax over 40 cols (input [N][48] fp16) ----------------

__launch_bounds__(256)
__global__ void k_lsm(const _Float16* __restrict__ z, float* __restrict__ out) {
    const int r = (blockIdx.x * blockDim.x + threadIdx.x) >> 6;
    const int lane = threadIdx.x & 63;
    if (r >= N_NODES) return;
    const bool act = lane < 40;
    float v = act ? (float)z[(size_t)r * 48 + lane] : -INFINITY;
    float m = v;
    for (int off = 32; off; off >>= 1) m = fmaxf(m, __shfl_xor(m, off));
    float ex = act ? __expf(v - m) : 0.f;
    float se = ex;
    for (int off = 32; off; off >>= 1) se += __shfl_xor(se, off);
    if (act) out[(size_t)r * 40 + lane] = v - m - __logf(se);
}

// ---------------- launch ----------------

extern "C" void kernel_launch(void* const* d_in, const int* in_sizes, int n_in,
                              void* d_out, int out_size, void* d_ws, size_t ws_size,
                              hipStream_t stream) {
    const float* x     = (const float*)d_in[0];
    const int*   ei    = (const int*)d_in[1];
    const float* W_in  = (const float*)d_in[2];
    const float* b_in  = (const float*)d_in[3];
    const float* W_mid = (const float*)d_in[4];
    const float* b_mid = (const float*)d_in[5];
    const float* W_out = (const float*)d_in[6];
    float* out = (float*)d_out;

    const int* srcv = ei;
    const int* dstv = ei + N_EDGES;

    char* w = (char*)d_ws;
    float* dinv   = (float*)(w);                       // 400 KB
    int* rowptr   = (int*)(w + (1ull << 19));          // 400 KB
    int* bcnt     = (int*)(w + (1ull << 20));
    int* bptr     = (int*)(w + (1ull << 20) + 4096);
    int* bcur     = (int*)(w + (1ull << 20) + 8192);
    int* colidx   = (int*)(w + (2ull << 20));          // 6.4 MB
    unsigned int* ebuf = (unsigned int*)(w + (9ull << 20));  // 6.4 MB
    _Float16* Wt1h = (_Float16*)(w + (16ull << 20));
    _Float16* Wt1l = Wt1h + 128 * 128;
    _Float16* Wt2h = Wt1l + 128 * 128;
    _Float16* Wt2l = Wt2h + 128 * 128;
    _Float16* Wt3h = Wt2l + 128 * 128;
    _Float16* Wt3l = Wt3h + 48 * 128;
    _Float16* hpA  = (_Float16*)(w + (18ull << 20));   // chunk-major, 25.6 MB
    _Float16* rmB  = (_Float16*)(w + (44ull << 20));   // row-major, 25.6 MB
    _Float16* zbuf = (_Float16*)(w + (70ull << 20));   // [N][48], 9.6 MB

    const int NB_PART = (N_EDGES + 4095) / 4096;  // 391

    // CSR build (bucketed)
    k_zero_int<<<2, 256, 0, stream>>>(bcnt, 512);
    k_bhist<<<NB_PART, 256, 0, stream>>>(dstv, bcnt);
    k_bscan<<<1, 512, 0, stream>>>(bcnt, bptr, bcur);
    k_bpart<<<NB_PART, 256, 0, stream>>>(srcv, dstv, bcur, ebuf);
    k_brow<<<NBUCK, 256, 0, stream>>>(ebuf, bptr, rowptr, dinv);
    k_bfill<<<NBUCK, 256, 0, stream>>>(ebuf, bptr, rowptr, colidx);

    // weight prep
    k_wprep<<<(128 * 128 + 255) / 256, 256, 0, stream>>>(W_in, 128, 128, Wt1h, Wt1l);
    k_wprep<<<(128 * 128 + 255) / 256, 256, 0, stream>>>(W_mid, 128, 128, Wt2h, Wt2l);
    k_wprep<<<(48 * 128 + 255) / 256, 256, 0, stream>>>(W_out, 40, 48, Wt3h, Wt3l);

    const int GEMM_BLOCKS = N_NODES / 32;
    const dim3 AGG8(( N_NODES + 63) / 64, 8);
    const dim3 AGG3((N_NODES + 63) / 64, 3);

    // Layer 1 (reads fp32 x directly)
    k_gemm128_f32<<<GEMM_BLOCKS, 256, 0, stream>>>(x, Wt1h, Wt1l, dinv, hpA);
    k_agg_chunk<128, true, true><<<AGG8, 256, 0, stream>>>(hpA, rowptr, colidx, dinv, b_in, rmB);
    // Layer 2
    k_gemm128<<<GEMM_BLOCKS, 256, 0, stream>>>(rmB, Wt2h, Wt2l, dinv, hpA);
    k_agg_chunk<128, true, true><<<AGG8, 256, 0, stream>>>(hpA, rowptr, colidx, dinv, b_mid, rmB);
    // Layer 3 (48-padded chunks) + log_softmax
    k_gemm40<<<(N_NODES + 127) / 128, 256, 0, stream>>>(rmB, Wt3h, Wt3l, dinv, hpA);
    k_agg_chunk<48, false, false><<<AGG3, 256, 0, stream>>>(hpA, rowptr, colidx, dinv, dinv, zbuf);
    k_lsm<<<(N_NODES * 64 + 255) / 256, 256, 0, stream>>>(zbuf, out);
}

// Round 6
// 451.570 us; speedup vs baseline: 2.0574x; 2.0574x over previous
//
#include <hip/hip_runtime.h>
#include <math.h>

#define N_NODES 100000
#define N_EDGES 1600000
#define NBUCK 391          // ceil(100000 / 256)

typedef __attribute__((ext_vector_type(8))) _Float16 h8v;
typedef __attribute__((ext_vector_type(4))) float f32x4;
typedef __attribute__((ext_vector_type(2))) _Float16 h2v;

// ---------------- CSR build (bucketed, packed) ----------------

__global__ void k_zero_int(int* __restrict__ p, int n) {
    int i = blockIdx.x * blockDim.x + threadIdx.x;
    if (i < n) p[i] = 0;
}

__launch_bounds__(256)
__global__ void k_bhist(const int* __restrict__ dstv, int* __restrict__ bcnt) {
    __shared__ int hist[NBUCK];
    const int tid = threadIdx.x;
    for (int t = tid; t < NBUCK; t += 256) hist[t] = 0;
    __syncthreads();
    const int base = blockIdx.x * 4096;
#pragma unroll
    for (int i = 0; i < 16; i++) {
        int e = base + i * 256 + tid;
        if (e < N_EDGES) atomicAdd(&hist[dstv[e] >> 8], 1);
    }
    __syncthreads();
    for (int t = tid; t < NBUCK; t += 256)
        if (hist[t]) atomicAdd(&bcnt[t], hist[t]);
}

__global__ void k_bscan(const int* __restrict__ bcnt, int* __restrict__ bptr,
                        int* __restrict__ bcur) {
    __shared__ int s[512];
    int tid = threadIdx.x;
    int v = (tid < NBUCK) ? bcnt[tid] : 0;
    int x = v;
    s[tid] = x;
    __syncthreads();
    for (int d = 1; d < 512; d <<= 1) {
        int t = (tid >= d) ? s[tid - d] : 0;
        __syncthreads();
        x += t;
        s[tid] = x;
        __syncthreads();
    }
    if (tid < NBUCK) {
        bptr[tid] = x - v;
        bcur[tid] = x - v;
    }
    if (tid == NBUCK - 1) bptr[NBUCK] = x;
}

__launch_bounds__(256)
__global__ void k_bpart(const int* __restrict__ srcv, const int* __restrict__ dstv,
                        int* __restrict__ bcur, unsigned int* __restrict__ ebuf) {
    __shared__ int hist[NBUCK];
    __shared__ int cur[NBUCK];
    const int tid = threadIdx.x;
    for (int t = tid; t < NBUCK; t += 256) hist[t] = 0;
    __syncthreads();
    const int base = blockIdx.x * 4096;
#pragma unroll
    for (int i = 0; i < 16; i++) {
        int e = base + i * 256 + tid;
        if (e < N_EDGES) atomicAdd(&hist[dstv[e] >> 8], 1);
    }
    __syncthreads();
    for (int t = tid; t < NBUCK; t += 256)
        cur[t] = hist[t] ? atomicAdd(&bcur[t], hist[t]) : 0;
    __syncthreads();
#pragma unroll
    for (int i = 0; i < 16; i++) {
        int e = base + i * 256 + tid;
        if (e < N_EDGES) {
            int d = dstv[e];
            int p = atomicAdd(&cur[d >> 8], 1);
            ebuf[p] = ((unsigned int)srcv[e] << 8) | (unsigned int)(d & 255);
        }
    }
}

__launch_bounds__(256)
__global__ void k_brow(const unsigned int* __restrict__ ebuf, const int* __restrict__ bptr,
                       int* __restrict__ rowptr, float* __restrict__ dinv) {
    __shared__ int cnt[256];
    __shared__ int s[256];
    const int tid = threadIdx.x;
    cnt[tid] = 0;
    __syncthreads();
    const int b = blockIdx.x;
    const int e0 = bptr[b], e1 = bptr[b + 1];
    for (int e = e0 + tid; e < e1; e += 256) atomicAdd(&cnt[ebuf[e] & 255u], 1);
    __syncthreads();
    int v = cnt[tid];
    int x = v;
    s[tid] = x;
    __syncthreads();
    for (int d = 1; d < 256; d <<= 1) {
        int t = (tid >= d) ? s[tid - d] : 0;
        __syncthreads();
        x += t;
        s[tid] = x;
        __syncthreads();
    }
    int node = b * 256 + tid;
    if (node < N_NODES) {
        rowptr[node] = e0 + x - v;
        dinv[node] = rsqrtf((float)(v + 1));  // +1 self-loop
        if (node == N_NODES - 1) rowptr[N_NODES] = N_EDGES;
    }
}

__launch_bounds__(256)
__global__ void k_bfill(const unsigned int* __restrict__ ebuf, const int* __restrict__ bptr,
                        const int* __restrict__ rowptr, int* __restrict__ colidx) {
    __shared__ int cur[256];
    const int tid = threadIdx.x;
    const int b = blockIdx.x;
    int node = b * 256 + tid;
    cur[tid] = (node < N_NODES) ? rowptr[node] : 0;
    __syncthreads();
    const int e0 = bptr[b], e1 = bptr[b + 1];
    for (int e = e0 + tid; e < e1; e += 256) {
        unsigned int sd = ebuf[e];
        int pos = atomicAdd(&cur[sd & 255u], 1);
        colidx[pos] = (int)(sd >> 8);
    }
}

// ---------------- weight conversion ----------------

__global__ void k_wprep(const float* __restrict__ W, int ncols, int ntcols,
                        _Float16* __restrict__ Wthi, _Float16* __restrict__ Wtlo) {
    int idx = blockIdx.x * blockDim.x + threadIdx.x;
    if (idx >= ntcols * 128) return;
    int n = idx / 128, k = idx % 128;
    float v = (n < ncols) ? W[k * ncols + n] : 0.f;
    _Float16 hi = (_Float16)v;
    _Float16 lo = (_Float16)(v - (float)hi);
    Wthi[n * 128 + k] = hi;
    Wtlo[n * 128 + k] = lo;
}

// ---------------- MFMA GEMMs (W = Whi+Wlo split f16), row-major fp16 out ----------------

__launch_bounds__(256)
__global__ void k_gemm128_f32(const float* __restrict__ Af,
                              const _Float16* __restrict__ Wthi, const _Float16* __restrict__ Wtlo,
                              const float* __restrict__ dinv, _Float16* __restrict__ out) {
    const int lane = threadIdx.x & 63;
    const int wi = threadIdx.x >> 6;
    const int r0 = blockIdx.x * 32;
    const int nb = wi * 32;
    const int nn = lane & 15;
    const int kq = (lane >> 4) * 8;

    h8v bh[4][2], bl[4][2];
#pragma unroll
    for (int c = 0; c < 4; c++)
#pragma unroll
        for (int t = 0; t < 2; t++) {
            int off = (nb + t * 16 + nn) * 128 + c * 32 + kq;
            bh[c][t] = *(const h8v*)(Wthi + off);
            bl[c][t] = *(const h8v*)(Wtlo + off);
        }

    f32x4 acc[2][2] = {};
#pragma unroll
    for (int c = 0; c < 4; c++) {
        h8v a[2];
#pragma unroll
        for (int m = 0; m < 2; m++) {
            const float* p = Af + (size_t)(r0 + m * 16 + nn) * 128 + c * 32 + kq;
            float4 p0 = *(const float4*)p;
            float4 p1 = *(const float4*)(p + 4);
            h8v av = {(_Float16)p0.x, (_Float16)p0.y, (_Float16)p0.z, (_Float16)p0.w,
                      (_Float16)p1.x, (_Float16)p1.y, (_Float16)p1.z, (_Float16)p1.w};
            a[m] = av;
        }
#pragma unroll
        for (int m = 0; m < 2; m++)
#pragma unroll
            for (int t = 0; t < 2; t++) {
                acc[m][t] = __builtin_amdgcn_mfma_f32_16x16x32_f16(a[m], bh[c][t], acc[m][t], 0, 0, 0);
                acc[m][t] = __builtin_amdgcn_mfma_f32_16x16x32_f16(a[m], bl[c][t], acc[m][t], 0, 0, 0);
            }
    }

    const int quad = lane >> 4;
#pragma unroll
    for (int m = 0; m < 2; m++) {
#pragma unroll
        for (int reg = 0; reg < 4; reg++) {
            int r = r0 + m * 16 + quad * 4 + reg;
            float dv = dinv[r];
#pragma unroll
            for (int t = 0; t < 2; t++)
                out[(size_t)r * 128 + nb + t * 16 + nn] = (_Float16)(acc[m][t][reg] * dv);
        }
    }
}

__launch_bounds__(256)
__global__ void k_gemm128(const _Float16* __restrict__ A,
                          const _Float16* __restrict__ Wthi, const _Float16* __restrict__ Wtlo,
                          const float* __restrict__ dinv, _Float16* __restrict__ out) {
    const int lane = threadIdx.x & 63;
    const int wi = threadIdx.x >> 6;
    const int r0 = blockIdx.x * 32;
    const int nb = wi * 32;
    const int nn = lane & 15;
    const int kq = (lane >> 4) * 8;

    h8v bh[4][2], bl[4][2];
#pragma unroll
    for (int c = 0; c < 4; c++)
#pragma unroll
        for (int t = 0; t < 2; t++) {
            int off = (nb + t * 16 + nn) * 128 + c * 32 + kq;
            bh[c][t] = *(const h8v*)(Wthi + off);
            bl[c][t] = *(const h8v*)(Wtlo + off);
        }

    f32x4 acc[2][2] = {};
#pragma unroll
    for (int c = 0; c < 4; c++) {
        h8v a[2];
#pragma unroll
        for (int m = 0; m < 2; m++)
            a[m] = *(const h8v*)(A + (size_t)(r0 + m * 16 + nn) * 128 + c * 32 + kq);
#pragma unroll
        for (int m = 0; m < 2; m++)
#pragma unroll
            for (int t = 0; t < 2; t++) {
                acc[m][t] = __builtin_amdgcn_mfma_f32_16x16x32_f16(a[m], bh[c][t], acc[m][t], 0, 0, 0);
                acc[m][t] = __builtin_amdgcn_mfma_f32_16x16x32_f16(a[m], bl[c][t], acc[m][t], 0, 0, 0);
            }
    }

    const int quad = lane >> 4;
#pragma unroll
    for (int m = 0; m < 2; m++) {
#pragma unroll
        for (int reg = 0; reg < 4; reg++) {
            int r = r0 + m * 16 + quad * 4 + reg;
            float dv = dinv[r];
#pragma unroll
            for (int t = 0; t < 2; t++)
                out[(size_t)r * 128 + nb + t * 16 + nn] = (_Float16)(acc[m][t][reg] * dv);
        }
    }
}

// Layer-3 GEMM: 40 cols into [N][64]-stride buffer (cols 48..63 left untouched).
__launch_bounds__(256)
__global__ void k_gemm40(const _Float16* __restrict__ A,
                         const _Float16* __restrict__ Wthi, const _Float16* __restrict__ Wtlo,
                         const float* __restrict__ dinv, _Float16* __restrict__ out) {
    const int lane = threadIdx.x & 63;
    const int wi = threadIdx.x >> 6;
    const int r0 = (blockIdx.x * 4 + wi) * 32;
    const int nn = lane & 15;
    const int kq = (lane >> 4) * 8;

    h8v bh[4][3], bl[4][3];
#pragma unroll
    for (int c = 0; c < 4; c++)
#pragma unroll
        for (int t = 0; t < 3; t++) {
            int off = (t * 16 + nn) * 128 + c * 32 + kq;
            bh[c][t] = *(const h8v*)(Wthi + off);
            bl[c][t] = *(const h8v*)(Wtlo + off);
        }

    f32x4 acc[2][3] = {};
#pragma unroll
    for (int c = 0; c < 4; c++) {
        h8v a[2];
#pragma unroll
        for (int m = 0; m < 2; m++) {
            int rr = min(r0 + m * 16 + nn, N_NODES - 1);
            a[m] = *(const h8v*)(A + (size_t)rr * 128 + c * 32 + kq);
        }
#pragma unroll
        for (int m = 0; m < 2; m++)
#pragma unroll
            for (int t = 0; t < 3; t++) {
                acc[m][t] = __builtin_amdgcn_mfma_f32_16x16x32_f16(a[m], bh[c][t], acc[m][t], 0, 0, 0);
                acc[m][t] = __builtin_amdgcn_mfma_f32_16x16x32_f16(a[m], bl[c][t], acc[m][t], 0, 0, 0);
            }
    }

    const int quad = lane >> 4;
#pragma unroll
    for (int m = 0; m < 2; m++) {
#pragma unroll
        for (int reg = 0; reg < 4; reg++) {
            int r = r0 + m * 16 + quad * 4 + reg;
            if (r < N_NODES) {
                float dv = dinv[r];
#pragma unroll
                for (int t = 0; t < 3; t++)
                    out[(size_t)r * 64 + t * 16 + nn] = (_Float16)(acc[m][t][reg] * dv);
            }
        }
    }
}

// ---------------- Wide-gather aggregation (F=128) ----------------
// One wave per row. Lane L: edge-slot L/16, col-part L%16 (16 B of the row).
// One dwordx4 gather instruction covers 4 edges' full 256B rows (1 KB/instr).
// 16 edges (4 groups) unrolled per loop iter -> 4 KB in flight per wave.
// Accumulate packed fp16; cross-slot shuffle reduce; epilogue on lanes 0-15.

__launch_bounds__(256)
__global__ void k_aggw128(const _Float16* __restrict__ hp, const int* __restrict__ rowptr,
                          const int* __restrict__ colidx, const float* __restrict__ dinv,
                          const float* __restrict__ bias, _Float16* __restrict__ outp) {
    const int r = (blockIdx.x * blockDim.x + threadIdx.x) >> 6;
    if (r >= N_NODES) return;
    const int lane = threadIdx.x & 63;
    const int sub = lane >> 4;    // edge slot 0..3
    const int cp = lane & 15;     // 16B col-part

    const int e0 = rowptr[r], e1 = rowptr[r + 1];
    const int e1m = e1 - 1;
    h8v acc = {};
    for (int e = e0; e < e1; e += 16) {
        int i0 = e + sub, i1 = e + 4 + sub, i2 = e + 8 + sub, i3 = e + 12 + sub;
        int s0 = colidx[min(i0, e1m)];
        int s1 = colidx[min(i1, e1m)];
        int s2 = colidx[min(i2, e1m)];
        int s3 = colidx[min(i3, e1m)];
        h8v v0 = *(const h8v*)(hp + (size_t)s0 * 128 + cp * 8);
        h8v v1 = *(const h8v*)(hp + (size_t)s1 * 128 + cp * 8);
        h8v v2 = *(const h8v*)(hp + (size_t)s2 * 128 + cp * 8);
        h8v v3 = *(const h8v*)(hp + (size_t)s3 * 128 + cp * 8);
        if (i0 < e1) acc += v0;
        if (i1 < e1) acc += v1;
        if (i2 < e1) acc += v2;
        if (i3 < e1) acc += v3;
    }
    // reduce over the 4 edge slots (lanes L, L^16, L^32, L^48 share col-part)
#pragma unroll
    for (int j = 0; j < 8; j++) {
        float a = (float)acc[j];
        a += __shfl_xor(a, 16);
        a += __shfl_xor(a, 32);
        acc[j] = (_Float16)a;  // reuse acc as f16 carrier of the reduced value
    }
    if (lane < 16) {
        h8v sv = *(const h8v*)(hp + (size_t)r * 128 + cp * 8);  // self-loop
        float dv = dinv[r];
        const float* bp = bias + cp * 8;
        float4 b0 = *(const float4*)bp;
        float4 b1 = *(const float4*)(bp + 4);
        float bb[8] = {b0.x, b0.y, b0.z, b0.w, b1.x, b1.y, b1.z, b1.w};
        h8v o;
#pragma unroll
        for (int j = 0; j < 8; j++) {
            float s = (float)acc[j] + (float)sv[j];
            o[j] = (_Float16)fmaxf(fmaf(dv, s, bb[j]), 0.f);
        }
        *(h8v*)(outp + (size_t)r * 128 + cp * 8) = o;
    }
}

// ---------------- Wide-gather final aggregation (64-col stride, 40 real cols) ----------

__launch_bounds__(256)
__global__ void k_aggw64(const _Float16* __restrict__ hp, const int* __restrict__ rowptr,
                         const int* __restrict__ colidx, const float* __restrict__ dinv,
                         _Float16* __restrict__ outp) {
    const int r = (blockIdx.x * blockDim.x + threadIdx.x) >> 6;
    if (r >= N_NODES) return;
    const int lane = threadIdx.x & 63;
    const int sub = lane >> 3;    // edge slot 0..7
    const int cp = lane & 7;      // 16B col-part (8 x 16B = 128B row)

    const int e0 = rowptr[r], e1 = rowptr[r + 1];
    const int e1m = e1 - 1;
    h8v acc = {};
    for (int e = e0; e < e1; e += 16) {
        int i0 = e + sub, i1 = e + 8 + sub;
        int s0 = colidx[min(i0, e1m)];
        int s1 = colidx[min(i1, e1m)];
        h8v v0 = *(const h8v*)(hp + (size_t)s0 * 64 + cp * 8);
        h8v v1 = *(const h8v*)(hp + (size_t)s1 * 64 + cp * 8);
        if (i0 < e1) acc += v0;
        if (i1 < e1) acc += v1;
    }
#pragma unroll
    for (int j = 0; j < 8; j++) {
        float a = (float)acc[j];
        a += __shfl_xor(a, 8);
        a += __shfl_xor(a, 16);
        a += __shfl_xor(a, 32);
        acc[j] = (_Float16)a;
    }
    if (lane < 8) {
        h8v sv = *(const h8v*)(hp + (size_t)r * 64 + cp * 8);  // self-loop
        float dv = dinv[r];
        h8v o;
#pragma unroll
        for (int j = 0; j < 8; j++)
            o[j] = (_Float16)(dv * ((float)acc[j] + (float)sv[j]));
        *(h8v*)(outp + (size_t)r * 64 + cp * 8) = o;
    }
}

// ---------------- log_softmax over 40 cols (input [N][64] fp16) ----------------

__launch_bounds__(256)
__global__ void k_lsm(const _Float16* __restrict__ z, float* __restrict__ out) {
    const int r = (blockIdx.x * blockDim.x + threadIdx.x) >> 6;
    const int lane = threadIdx.x & 63;
    if (r >= N_NODES) return;
    const bool act = lane < 40;
    float v = act ? (float)z[(size_t)r * 64 + lane] : -INFINITY;
    float m = v;
    for (int off = 32; off; off >>= 1) m = fmaxf(m, __shfl_xor(m, off));
    float ex = act ? __expf(v - m) : 0.f;
    float se = ex;
    for (int off = 32; off; off >>= 1) se += __shfl_xor(se, off);
    if (act) out[(size_t)r * 40 + lane] = v - m - __logf(se);
}

// ---------------- launch ----------------

extern "C" void kernel_launch(void* const* d_in, const int* in_sizes, int n_in,
                              void* d_out, int out_size, void* d_ws, size_t ws_size,
                              hipStream_t stream) {
    const float* x     = (const float*)d_in[0];
    const int*   ei    = (const int*)d_in[1];
    const float* W_in  = (const float*)d_in[2];
    const float* b_in  = (const float*)d_in[3];
    const float* W_mid = (const float*)d_in[4];
    const float* b_mid = (const float*)d_in[5];
    const float* W_out = (const float*)d_in[6];
    float* out = (float*)d_out;

    const int* srcv = ei;
    const int* dstv = ei + N_EDGES;

    char* w = (char*)d_ws;
    float* dinv   = (float*)(w);                       // 400 KB
    int* rowptr   = (int*)(w + (1ull << 19));          // 400 KB
    int* bcnt     = (int*)(w + (1ull << 20));
    int* bptr     = (int*)(w + (1ull << 20) + 4096);
    int* bcur     = (int*)(w + (1ull << 20) + 8192);
    int* colidx   = (int*)(w + (2ull << 20));          // 6.4 MB
    unsigned int* ebuf = (unsigned int*)(w + (9ull << 20));  // 6.4 MB
    _Float16* Wt1h = (_Float16*)(w + (16ull << 20));
    _Float16* Wt1l = Wt1h + 128 * 128;
    _Float16* Wt2h = Wt1l + 128 * 128;
    _Float16* Wt2l = Wt2h + 128 * 128;
    _Float16* Wt3h = Wt2l + 128 * 128;
    _Float16* Wt3l = Wt3h + 48 * 128;
    _Float16* bufA = (_Float16*)(w + (18ull << 20));   // [N][128] fp16, 25.6 MB
    _Float16* bufB = (_Float16*)(w + (44ull << 20));   // [N][128] fp16, 25.6 MB
    _Float16* zbuf = (_Float16*)(w + (70ull << 20));   // [N][64] fp16, 12.8 MB

    const int NB_PART = (N_EDGES + 4095) / 4096;  // 391

    // CSR build (bucketed)
    k_zero_int<<<2, 256, 0, stream>>>(bcnt, 512);
    k_bhist<<<NB_PART, 256, 0, stream>>>(dstv, bcnt);
    k_bscan<<<1, 512, 0, stream>>>(bcnt, bptr, bcur);
    k_bpart<<<NB_PART, 256, 0, stream>>>(srcv, dstv, bcur, ebuf);
    k_brow<<<NBUCK, 256, 0, stream>>>(ebuf, bptr, rowptr, dinv);
    k_bfill<<<NBUCK, 256, 0, stream>>>(ebuf, bptr, rowptr, colidx);

    // weight prep
    k_wprep<<<(128 * 128 + 255) / 256, 256, 0, stream>>>(W_in, 128, 128, Wt1h, Wt1l);
    k_wprep<<<(128 * 128 + 255) / 256, 256, 0, stream>>>(W_mid, 128, 128, Wt2h, Wt2l);
    k_wprep<<<(48 * 128 + 255) / 256, 256, 0, stream>>>(W_out, 40, 48, Wt3h, Wt3l);

    const int AGG_BLOCKS = N_NODES / 4;
    const int GEMM_BLOCKS = N_NODES / 32;

    // Layer 1 (reads fp32 x directly)
    k_gemm128_f32<<<GEMM_BLOCKS, 256, 0, stream>>>(x, Wt1h, Wt1l, dinv, bufA);
    k_aggw128<<<AGG_BLOCKS, 256, 0, stream>>>(bufA, rowptr, colidx, dinv, b_in, bufB);
    // Layer 2
    k_gemm128<<<GEMM_BLOCKS, 256, 0, stream>>>(bufB, Wt2h, Wt2l, dinv, bufA);
    k_aggw128<<<AGG_BLOCKS, 256, 0, stream>>>(bufA, rowptr, colidx, dinv, b_mid, bufB);
    // Layer 3 (64-stride padded) + log_softmax
    k_gemm40<<<(N_NODES + 127) / 128, 256, 0, stream>>>(bufB, Wt3h, Wt3l, dinv, zbuf);
    k_aggw64<<<AGG_BLOCKS, 256, 0, stream>>>(zbuf, rowptr, colidx, dinv, bufA);
    k_lsm<<<(N_NODES * 64 + 255) / 256, 256, 0, stream>>>(bufA, out);
}

// Round 7
// 399.449 us; speedup vs baseline: 2.3259x; 1.1305x over previous
//
#include <hip/hip_runtime.h>
#include <math.h>

#define N_NODES 100000
#define N_EDGES 1600000
#define NBUCK 391          // ceil(100000 / 256)
#define BSTRIDE 4608       // bucket slack stride: mean 4096 + 8 sigma

typedef __attribute__((ext_vector_type(8))) _Float16 h8v;
typedef __attribute__((ext_vector_type(4))) float f32x4;

// ---------------- CSR build: 2 kernels + 1 memset ----------------

// Partition packed (src<<8 | dst&255) into slack-strided bucket regions.
// Reservation directly on global bcnt (zeroed by memsetAsync) - no pre-scan.
__launch_bounds__(256)
__global__ void k_bpart(const int* __restrict__ srcv, const int* __restrict__ dstv,
                        int* __restrict__ bcnt, unsigned int* __restrict__ ebuf) {
    __shared__ int hist[NBUCK];
    __shared__ int cur[NBUCK];
    const int tid = threadIdx.x;
    for (int t = tid; t < NBUCK; t += 256) hist[t] = 0;
    __syncthreads();
    const int base = blockIdx.x * 4096;
#pragma unroll
    for (int i = 0; i < 16; i++) {
        int e = base + i * 256 + tid;
        if (e < N_EDGES) atomicAdd(&hist[dstv[e] >> 8], 1);
    }
    __syncthreads();
    for (int t = tid; t < NBUCK; t += 256)
        if (hist[t]) cur[t] = t * BSTRIDE + atomicAdd(&bcnt[t], hist[t]);
    __syncthreads();
#pragma unroll
    for (int i = 0; i < 16; i++) {
        int e = base + i * 256 + tid;
        if (e < N_EDGES) {
            int d = dstv[e];
            int p = atomicAdd(&cur[d >> 8], 1);
            ebuf[p] = ((unsigned int)srcv[e] << 8) | (unsigned int)(d & 255);
        }
    }
}

// Per bucket: degree histogram + scan -> rowse(start,end) + dinv, then colidx fill.
__launch_bounds__(256)
__global__ void k_bucket(const unsigned int* __restrict__ ebuf, const int* __restrict__ bcnt,
                         int2* __restrict__ rowse, float* __restrict__ dinv,
                         int* __restrict__ colidx) {
    __shared__ int cnt[256];
    __shared__ int s[256];
    __shared__ int cur[256];
    const int tid = threadIdx.x;
    const int b = blockIdx.x;
    const int e0 = b * BSTRIDE;
    const int e1 = e0 + bcnt[b];
    cnt[tid] = 0;
    __syncthreads();
    for (int e = e0 + tid; e < e1; e += 256) atomicAdd(&cnt[ebuf[e] & 255u], 1);
    __syncthreads();
    int v = cnt[tid];
    int x = v;
    s[tid] = x;
    __syncthreads();
    for (int d = 1; d < 256; d <<= 1) {
        int t = (tid >= d) ? s[tid - d] : 0;
        __syncthreads();
        x += t;
        s[tid] = x;
        __syncthreads();
    }
    int start = e0 + x - v;
    int node = b * 256 + tid;
    if (node < N_NODES) {
        rowse[node] = make_int2(start, start + v);
        dinv[node] = rsqrtf((float)(v + 1));  // +1 self-loop
    }
    cur[tid] = start;
    __syncthreads();
    for (int e = e0 + tid; e < e1; e += 256) {
        unsigned int sd = ebuf[e];
        int pos = atomicAdd(&cur[sd & 255u], 1);
        colidx[pos] = (int)(sd >> 8);
    }
}

// Zero the sentinel rows (index N_NODES) of the gather buffers.
__global__ void k_zrows(_Float16* __restrict__ bufA, _Float16* __restrict__ zbuf) {
    int t = threadIdx.x;
    if (t < 128) bufA[(size_t)N_NODES * 128 + t] = (_Float16)0.f;
    if (t < 64)  zbuf[(size_t)N_NODES * 64 + t] = (_Float16)0.f;
}

// ---------------- fused weight prep: all three W -> transposed f16 hi/lo ----------------
// Wt layout: [W1h 128x128][W1l][W2h][W2l][W3h 48x128][W3l 48x128]

__global__ void k_wprep_all(const float* __restrict__ W1, const float* __restrict__ W2,
                            const float* __restrict__ W3, _Float16* __restrict__ Wt) {
    int idx = blockIdx.x * blockDim.x + threadIdx.x;
    if (idx >= 304 * 128) return;
    int n = idx / 128, k = idx % 128;
    const float* W;
    int ncols, nloc;
    _Float16 *ph, *pl;
    if (n < 128)      { W = W1; ncols = 128; nloc = n;       ph = Wt;                 pl = Wt + 128 * 128; }
    else if (n < 256) { W = W2; ncols = 128; nloc = n - 128; ph = Wt + 2 * 128 * 128; pl = Wt + 3 * 128 * 128; }
    else              { W = W3; ncols = 40;  nloc = n - 256; ph = Wt + 4 * 128 * 128; pl = Wt + 4 * 128 * 128 + 48 * 128; }
    float v = (nloc < ncols) ? W[k * ncols + nloc] : 0.f;
    _Float16 hi = (_Float16)v;
    _Float16 lo = (_Float16)(v - (float)hi);
    ph[nloc * 128 + k] = hi;
    pl[nloc * 128 + k] = lo;
}

// ---------------- MFMA GEMMs (W = Whi+Wlo split f16), row-major fp16 out ----------------

__launch_bounds__(256)
__global__ void k_gemm128_f32(const float* __restrict__ Af,
                              const _Float16* __restrict__ Wthi, const _Float16* __restrict__ Wtlo,
                              const float* __restrict__ dinv, _Float16* __restrict__ out) {
    const int lane = threadIdx.x & 63;
    const int wi = threadIdx.x >> 6;
    const int r0 = blockIdx.x * 32;
    const int nb = wi * 32;
    const int nn = lane & 15;
    const int kq = (lane >> 4) * 8;

    h8v bh[4][2], bl[4][2];
#pragma unroll
    for (int c = 0; c < 4; c++)
#pragma unroll
        for (int t = 0; t < 2; t++) {
            int off = (nb + t * 16 + nn) * 128 + c * 32 + kq;
            bh[c][t] = *(const h8v*)(Wthi + off);
            bl[c][t] = *(const h8v*)(Wtlo + off);
        }

    f32x4 acc[2][2] = {};
#pragma unroll
    for (int c = 0; c < 4; c++) {
        h8v a[2];
#pragma unroll
        for (int m = 0; m < 2; m++) {
            const float* p = Af + (size_t)(r0 + m * 16 + nn) * 128 + c * 32 + kq;
            float4 p0 = *(const float4*)p;
            float4 p1 = *(const float4*)(p + 4);
            h8v av = {(_Float16)p0.x, (_Float16)p0.y, (_Float16)p0.z, (_Float16)p0.w,
                      (_Float16)p1.x, (_Float16)p1.y, (_Float16)p1.z, (_Float16)p1.w};
            a[m] = av;
        }
#pragma unroll
        for (int m = 0; m < 2; m++)
#pragma unroll
            for (int t = 0; t < 2; t++) {
                acc[m][t] = __builtin_amdgcn_mfma_f32_16x16x32_f16(a[m], bh[c][t], acc[m][t], 0, 0, 0);
                acc[m][t] = __builtin_amdgcn_mfma_f32_16x16x32_f16(a[m], bl[c][t], acc[m][t], 0, 0, 0);
            }
    }

    const int quad = lane >> 4;
#pragma unroll
    for (int m = 0; m < 2; m++) {
#pragma unroll
        for (int reg = 0; reg < 4; reg++) {
            int r = r0 + m * 16 + quad * 4 + reg;
            float dv = dinv[r];
#pragma unroll
            for (int t = 0; t < 2; t++)
                out[(size_t)r * 128 + nb + t * 16 + nn] = (_Float16)(acc[m][t][reg] * dv);
        }
    }
}

__launch_bounds__(256)
__global__ void k_gemm128(const _Float16* __restrict__ A,
                          const _Float16* __restrict__ Wthi, const _Float16* __restrict__ Wtlo,
                          const float* __restrict__ dinv, _Float16* __restrict__ out) {
    const int lane = threadIdx.x & 63;
    const int wi = threadIdx.x >> 6;
    const int r0 = blockIdx.x * 32;
    const int nb = wi * 32;
    const int nn = lane & 15;
    const int kq = (lane >> 4) * 8;

    h8v bh[4][2], bl[4][2];
#pragma unroll
    for (int c = 0; c < 4; c++)
#pragma unroll
        for (int t = 0; t < 2; t++) {
            int off = (nb + t * 16 + nn) * 128 + c * 32 + kq;
            bh[c][t] = *(const h8v*)(Wthi + off);
            bl[c][t] = *(const h8v*)(Wtlo + off);
        }

    f32x4 acc[2][2] = {};
#pragma unroll
    for (int c = 0; c < 4; c++) {
        h8v a[2];
#pragma unroll
        for (int m = 0; m < 2; m++)
            a[m] = *(const h8v*)(A + (size_t)(r0 + m * 16 + nn) * 128 + c * 32 + kq);
#pragma unroll
        for (int m = 0; m < 2; m++)
#pragma unroll
            for (int t = 0; t < 2; t++) {
                acc[m][t] = __builtin_amdgcn_mfma_f32_16x16x32_f16(a[m], bh[c][t], acc[m][t], 0, 0, 0);
                acc[m][t] = __builtin_amdgcn_mfma_f32_16x16x32_f16(a[m], bl[c][t], acc[m][t], 0, 0, 0);
            }
    }

    const int quad = lane >> 4;
#pragma unroll
    for (int m = 0; m < 2; m++) {
#pragma unroll
        for (int reg = 0; reg < 4; reg++) {
            int r = r0 + m * 16 + quad * 4 + reg;
            float dv = dinv[r];
#pragma unroll
            for (int t = 0; t < 2; t++)
                out[(size_t)r * 128 + nb + t * 16 + nn] = (_Float16)(acc[m][t][reg] * dv);
        }
    }
}

// Layer-3 GEMM: 40 real cols (48 written) into [N+1][64]-stride buffer.
__launch_bounds__(256)
__global__ void k_gemm40(const _Float16* __restrict__ A,
                         const _Float16* __restrict__ Wthi, const _Float16* __restrict__ Wtlo,
                         const float* __restrict__ dinv, _Float16* __restrict__ out) {
    const int lane = threadIdx.x & 63;
    const int wi = threadIdx.x >> 6;
    const int r0 = (blockIdx.x * 4 + wi) * 32;
    const int nn = lane & 15;
    const int kq = (lane >> 4) * 8;

    h8v bh[4][3], bl[4][3];
#pragma unroll
    for (int c = 0; c < 4; c++)
#pragma unroll
        for (int t = 0; t < 3; t++) {
            int off = (t * 16 + nn) * 128 + c * 32 + kq;
            bh[c][t] = *(const h8v*)(Wthi + off);
            bl[c][t] = *(const h8v*)(Wtlo + off);
        }

    f32x4 acc[2][3] = {};
#pragma unroll
    for (int c = 0; c < 4; c++) {
        h8v a[2];
#pragma unroll
        for (int m = 0; m < 2; m++) {
            int rr = min(r0 + m * 16 + nn, N_NODES - 1);
            a[m] = *(const h8v*)(A + (size_t)rr * 128 + c * 32 + kq);
        }
#pragma unroll
        for (int m = 0; m < 2; m++)
#pragma unroll
            for (int t = 0; t < 3; t++) {
                acc[m][t] = __builtin_amdgcn_mfma_f32_16x16x32_f16(a[m], bh[c][t], acc[m][t], 0, 0, 0);
                acc[m][t] = __builtin_amdgcn_mfma_f32_16x16x32_f16(a[m], bl[c][t], acc[m][t], 0, 0, 0);
            }
    }

    const int quad = lane >> 4;
#pragma unroll
    for (int m = 0; m < 2; m++) {
#pragma unroll
        for (int reg = 0; reg < 4; reg++) {
            int r = r0 + m * 16 + quad * 4 + reg;
            if (r < N_NODES) {
                float dv = dinv[r];
#pragma unroll
                for (int t = 0; t < 3; t++)
                    out[(size_t)r * 64 + t * 16 + nn] = (_Float16)(acc[m][t][reg] * dv);
            }
        }
    }
}

// ---------------- Slot-parallel aggregation (F=128) ----------------
// Wave = 4 row-slots x 16 col-parts (16 B). Each slot owns one full 256 B row:
// no cross-lane reduce. Dead edges gather the zero row at index N_NODES.
// Stores: 4 consecutive rows per wave -> fully coalesced 1 KB.

__launch_bounds__(256)
__global__ void k_agg4(const _Float16* __restrict__ hp, const int2* __restrict__ rowse,
                       const int* __restrict__ colidx, const float* __restrict__ bias,
                       _Float16* __restrict__ outp) {
    const int lane = threadIdx.x & 63;
    const int wid = (blockIdx.x * blockDim.x + threadIdx.x) >> 6;
    const int rs = lane >> 4;   // row slot 0..3
    const int cp = lane & 15;   // 16B col part
    const int r = wid * 4 + rs; // 25000 waves x 4 = 100000 exactly

    const int2 se = rowse[r];
    const int deg = se.y - se.x;
    int m = deg;
    m = max(m, __shfl_xor(m, 16));
    m = max(m, __shfl_xor(m, 32));

    const _Float16* hpc = hp + cp * 8;
    h8v acc = {};
    for (int it = 0; it < m; it += 4) {
        int i0 = se.x + it;
        int s0 = colidx[i0];
        int s1 = colidx[i0 + 1];
        int s2 = colidx[i0 + 2];
        int s3 = colidx[i0 + 3];
        s0 = (it < deg) ? s0 : N_NODES;
        s1 = (it + 1 < deg) ? s1 : N_NODES;
        s2 = (it + 2 < deg) ? s2 : N_NODES;
        s3 = (it + 3 < deg) ? s3 : N_NODES;
        h8v v0 = *(const h8v*)(hpc + (size_t)s0 * 128);
        h8v v1 = *(const h8v*)(hpc + (size_t)s1 * 128);
        h8v v2 = *(const h8v*)(hpc + (size_t)s2 * 128);
        h8v v3 = *(const h8v*)(hpc + (size_t)s3 * 128);
        acc += v0;
        acc += v1;
        acc += v2;
        acc += v3;
    }

    h8v sv = *(const h8v*)(hpc + (size_t)r * 128);  // self-loop
    float dv = rsqrtf((float)(deg + 1));
    const float* bp = bias + cp * 8;
    float4 b0 = *(const float4*)bp;
    float4 b1 = *(const float4*)(bp + 4);
    float bb[8] = {b0.x, b0.y, b0.z, b0.w, b1.x, b1.y, b1.z, b1.w};
    h8v o;
#pragma unroll
    for (int j = 0; j < 8; j++) {
        float s = (float)acc[j] + (float)sv[j];
        o[j] = (_Float16)fmaxf(fmaf(dv, s, bb[j]), 0.f);
    }
    *(h8v*)(outp + (size_t)r * 128 + cp * 8) = o;
}

// ---------------- Final aggregation (64-stride rows) + fused log_softmax ----------------
// Wave = 8 row-slots x 8 col-parts (16 B each = 128 B row). Slot-local lsm
// reduce over 8 lanes (cols 0..39 live in cp 0..4).

__launch_bounds__(256)
__global__ void k_agg_out(const _Float16* __restrict__ hp, const int2* __restrict__ rowse,
                          const int* __restrict__ colidx, float* __restrict__ out) {
    const int lane = threadIdx.x & 63;
    const int wid = (blockIdx.x * blockDim.x + threadIdx.x) >> 6;
    const int rs = lane >> 3;   // row slot 0..7
    const int cp = lane & 7;    // 16B col part
    const int r = wid * 8 + rs; // 12500 waves x 8 = 100000 exactly

    const int2 se = rowse[r];
    const int deg = se.y - se.x;
    int m = deg;
    m = max(m, __shfl_xor(m, 8));
    m = max(m, __shfl_xor(m, 16));
    m = max(m, __shfl_xor(m, 32));

    const _Float16* hpc = hp + cp * 8;
    h8v acc = {};
    for (int it = 0; it < m; it += 4) {
        int i0 = se.x + it;
        int s0 = colidx[i0];
        int s1 = colidx[i0 + 1];
        int s2 = colidx[i0 + 2];
        int s3 = colidx[i0 + 3];
        s0 = (it < deg) ? s0 : N_NODES;
        s1 = (it + 1 < deg) ? s1 : N_NODES;
        s2 = (it + 2 < deg) ? s2 : N_NODES;
        s3 = (it + 3 < deg) ? s3 : N_NODES;
        h8v v0 = *(const h8v*)(hpc + (size_t)s0 * 64);
        h8v v1 = *(const h8v*)(hpc + (size_t)s1 * 64);
        h8v v2 = *(const h8v*)(hpc + (size_t)s2 * 64);
        h8v v3 = *(const h8v*)(hpc + (size_t)s3 * 64);
        acc += v0;
        acc += v1;
        acc += v2;
        acc += v3;
    }

    h8v sv = *(const h8v*)(hpc + (size_t)r * 64);  // self-loop
    float dv = rsqrtf((float)(deg + 1));
    float z[8];
#pragma unroll
    for (int j = 0; j < 8; j++) z[j] = dv * ((float)acc[j] + (float)sv[j]);

    const bool act = cp < 5;  // cols 0..39
    float pm = -INFINITY;
    if (act) {
#pragma unroll
        for (int j = 0; j < 8; j++) pm = fmaxf(pm, z[j]);
    }
    pm = fmaxf(pm, __shfl_xor(pm, 1));
    pm = fmaxf(pm, __shfl_xor(pm, 2));
    pm = fmaxf(pm, __shfl_xor(pm, 4));
    float pe = 0.f;
    if (act) {
#pragma unroll
        for (int j = 0; j < 8; j++) pe += __expf(z[j] - pm);
    }
    pe += __shfl_xor(pe, 1);
    pe += __shfl_xor(pe, 2);
    pe += __shfl_xor(pe, 4);
    float lse = __logf(pe);
    if (act) {
        float* po = out + (size_t)r * 40 + cp * 8;
        float4 o0 = make_float4(z[0] - pm - lse, z[1] - pm - lse, z[2] - pm - lse, z[3] - pm - lse);
        float4 o1 = make_float4(z[4] - pm - lse, z[5] - pm - lse, z[6] - pm - lse, z[7] - pm - lse);
        *(float4*)po = o0;
        *(float4*)(po + 4) = o1;
    }
}

// ---------------- launch ----------------

extern "C" void kernel_launch(void* const* d_in, const int* in_sizes, int n_in,
                              void* d_out, int out_size, void* d_ws, size_t ws_size,
                              hipStream_t stream) {
    const float* x     = (const float*)d_in[0];
    const int*   ei    = (const int*)d_in[1];
    const float* W_in  = (const float*)d_in[2];
    const float* b_in  = (const float*)d_in[3];
    const float* W_mid = (const float*)d_in[4];
    const float* b_mid = (const float*)d_in[5];
    const float* W_out = (const float*)d_in[6];
    float* out = (float*)d_out;

    const int* srcv = ei;
    const int* dstv = ei + N_EDGES;

    char* w = (char*)d_ws;
    float* dinv   = (float*)(w);                              // 400 KB
    int2* rowse   = (int2*)(w + (1ull << 19));                // 800 KB
    int* bcnt     = (int*)(w + 1507328);                      // 2 KB
    int* colidx   = (int*)(w + (2ull << 20));                 // 7.2 MB + pad
    unsigned int* ebuf = (unsigned int*)(w + (10ull << 20));  // 7.2 MB
    _Float16* Wt  = (_Float16*)(w + (18ull << 20));           // 155 KB
    _Float16* bufA = (_Float16*)(w + (19ull << 20));          // (N+1)*128 fp16, 25.6 MB
    _Float16* bufB = (_Float16*)(w + (45ull << 20));          // (N+1)*128 fp16, 25.6 MB
    _Float16* zbuf = (_Float16*)(w + (71ull << 20));          // (N+1)*64 fp16, 12.8 MB

    _Float16* W1h = Wt;
    _Float16* W1l = Wt + 128 * 128;
    _Float16* W2h = Wt + 2 * 128 * 128;
    _Float16* W2l = Wt + 3 * 128 * 128;
    _Float16* W3h = Wt + 4 * 128 * 128;
    _Float16* W3l = Wt + 4 * 128 * 128 + 48 * 128;

    const int NB_PART = (N_EDGES + 4095) / 4096;  // 391

    // CSR build
    hipMemsetAsync(bcnt, 0, NBUCK * sizeof(int), stream);
    k_zrows<<<1, 256, 0, stream>>>(bufA, zbuf);
    k_bpart<<<NB_PART, 256, 0, stream>>>(srcv, dstv, bcnt, ebuf);
    k_bucket<<<NBUCK, 256, 0, stream>>>(ebuf, bcnt, rowse, dinv, colidx);

    // weight prep (one launch)
    k_wprep_all<<<(304 * 128 + 255) / 256, 256, 0, stream>>>(W_in, W_mid, W_out, Wt);

    const int GEMM_BLOCKS = N_NODES / 32;   // 3125
    const int AGG4_BLOCKS = N_NODES / 16;   // 6250 (4 waves x 4 rows)
    const int AGGO_BLOCKS = N_NODES / 32;   // 3125 (4 waves x 8 rows)

    // Layer 1 (reads fp32 x directly)
    k_gemm128_f32<<<GEMM_BLOCKS, 256, 0, stream>>>(x, W1h, W1l, dinv, bufA);
    k_agg4<<<AGG4_BLOCKS, 256, 0, stream>>>(bufA, rowse, colidx, b_in, bufB);
    // Layer 2
    k_gemm128<<<GEMM_BLOCKS, 256, 0, stream>>>(bufB, W2h, W2l, dinv, bufA);
    k_agg4<<<AGG4_BLOCKS, 256, 0, stream>>>(bufA, rowse, colidx, b_mid, bufB);
    // Layer 3 + fused log_softmax
    k_gemm40<<<(N_NODES + 127) / 128, 256, 0, stream>>>(bufB, W3h, W3l, dinv, zbuf);
    k_agg_out<<<AGGO_BLOCKS, 256, 0, stream>>>(zbuf, rowse, colidx, out);
}

// Round 8
// 367.684 us; speedup vs baseline: 2.5268x; 1.0864x over previous
//
#include <hip/hip_runtime.h>
#include <math.h>

#define N_NODES 100000
#define N_EDGES 1600000
#define NBUCK 391          // ceil(100000 / 256)
#define BSTRIDE 4608       // bucket slack stride: mean 4096 + 8 sigma

typedef __attribute__((ext_vector_type(8))) _Float16 h8v;
typedef __attribute__((ext_vector_type(4))) float f32x4;

// ---------------- CSR build: 2 kernels + 1 memset ----------------

__launch_bounds__(256)
__global__ void k_bpart(const int* __restrict__ srcv, const int* __restrict__ dstv,
                        int* __restrict__ bcnt, unsigned int* __restrict__ ebuf) {
    __shared__ int hist[NBUCK];
    __shared__ int cur[NBUCK];
    const int tid = threadIdx.x;
    for (int t = tid; t < NBUCK; t += 256) hist[t] = 0;
    __syncthreads();
    const int base = blockIdx.x * 4096;
#pragma unroll
    for (int i = 0; i < 16; i++) {
        int e = base + i * 256 + tid;
        if (e < N_EDGES) atomicAdd(&hist[dstv[e] >> 8], 1);
    }
    __syncthreads();
    for (int t = tid; t < NBUCK; t += 256)
        if (hist[t]) cur[t] = t * BSTRIDE + atomicAdd(&bcnt[t], hist[t]);
    __syncthreads();
#pragma unroll
    for (int i = 0; i < 16; i++) {
        int e = base + i * 256 + tid;
        if (e < N_EDGES) {
            int d = dstv[e];
            int p = atomicAdd(&cur[d >> 8], 1);
            ebuf[p] = ((unsigned int)srcv[e] << 8) | (unsigned int)(d & 255);
        }
    }
}

__launch_bounds__(256)
__global__ void k_bucket(const unsigned int* __restrict__ ebuf, const int* __restrict__ bcnt,
                         int2* __restrict__ rowse, float* __restrict__ dinv,
                         int* __restrict__ colidx) {
    __shared__ int cnt[256];
    __shared__ int s[256];
    __shared__ int cur[256];
    const int tid = threadIdx.x;
    const int b = blockIdx.x;
    const int e0 = b * BSTRIDE;
    const int e1 = e0 + bcnt[b];
    cnt[tid] = 0;
    __syncthreads();
    for (int e = e0 + tid; e < e1; e += 256) atomicAdd(&cnt[ebuf[e] & 255u], 1);
    __syncthreads();
    int v = cnt[tid];
    int x = v;
    s[tid] = x;
    __syncthreads();
    for (int d = 1; d < 256; d <<= 1) {
        int t = (tid >= d) ? s[tid - d] : 0;
        __syncthreads();
        x += t;
        s[tid] = x;
        __syncthreads();
    }
    int start = e0 + x - v;
    int node = b * 256 + tid;
    if (node < N_NODES) {
        rowse[node] = make_int2(start, start + v);
        dinv[node] = rsqrtf((float)(v + 1));  // +1 self-loop
    }
    cur[tid] = start;
    __syncthreads();
    for (int e = e0 + tid; e < e1; e += 256) {
        unsigned int sd = ebuf[e];
        int pos = atomicAdd(&cur[sd & 255u], 1);
        colidx[pos] = (int)(sd >> 8);
    }
}

// Zero the sentinel rows (index N_NODES) of the gather buffers.
__global__ void k_zrows(_Float16* __restrict__ bufA, _Float16* __restrict__ zbuf) {
    int t = threadIdx.x;
    if (t < 128) bufA[(size_t)N_NODES * 128 + t] = (_Float16)0.f;
    if (t < 64)  zbuf[(size_t)N_NODES * 64 + t] = (_Float16)0.f;
}

// ---------------- fused weight prep ----------------

__global__ void k_wprep_all(const float* __restrict__ W1, const float* __restrict__ W2,
                            const float* __restrict__ W3, _Float16* __restrict__ Wt) {
    int idx = blockIdx.x * blockDim.x + threadIdx.x;
    if (idx >= 304 * 128) return;
    int n = idx / 128, k = idx % 128;
    const float* W;
    int ncols, nloc;
    _Float16 *ph, *pl;
    if (n < 128)      { W = W1; ncols = 128; nloc = n;       ph = Wt;                 pl = Wt + 128 * 128; }
    else if (n < 256) { W = W2; ncols = 128; nloc = n - 128; ph = Wt + 2 * 128 * 128; pl = Wt + 3 * 128 * 128; }
    else              { W = W3; ncols = 40;  nloc = n - 256; ph = Wt + 4 * 128 * 128; pl = Wt + 4 * 128 * 128 + 48 * 128; }
    float v = (nloc < ncols) ? W[k * ncols + nloc] : 0.f;
    _Float16 hi = (_Float16)v;
    _Float16 lo = (_Float16)(v - (float)hi);
    ph[nloc * 128 + k] = hi;
    pl[nloc * 128 + k] = lo;
}

// ---------------- Persistent-B MFMA GEMMs ----------------
// B fragments (hi+lo, 64 VGPRs) loaded ONCE per wave; grid-stride loop over
// 32-row tiles. Per tile: 8 independent A-loads + 16 MFMAs (4 acc chains).
// 625 blocks x 5 tiles = 3125 tiles exactly.

#define GEMM_GRID 625
#define NTILES 3125

__launch_bounds__(256, 2)
__global__ void k_gemm128_f32(const float* __restrict__ Af,
                              const _Float16* __restrict__ Wthi, const _Float16* __restrict__ Wtlo,
                              const float* __restrict__ dinv, _Float16* __restrict__ out) {
    const int lane = threadIdx.x & 63;
    const int wi = threadIdx.x >> 6;
    const int nb = wi * 32;
    const int nn = lane & 15;
    const int kq = (lane >> 4) * 8;
    const int quad = lane >> 4;

    h8v bh[4][2], bl[4][2];
#pragma unroll
    for (int c = 0; c < 4; c++)
#pragma unroll
        for (int t = 0; t < 2; t++) {
            int off = (nb + t * 16 + nn) * 128 + c * 32 + kq;
            bh[c][t] = *(const h8v*)(Wthi + off);
            bl[c][t] = *(const h8v*)(Wtlo + off);
        }

    for (int rt = blockIdx.x; rt < NTILES; rt += GEMM_GRID) {
        const int r0 = rt * 32;
        f32x4 acc[2][2] = {};
#pragma unroll
        for (int c = 0; c < 4; c++) {
            h8v a[2];
#pragma unroll
            for (int m = 0; m < 2; m++) {
                const float* p = Af + (size_t)(r0 + m * 16 + nn) * 128 + c * 32 + kq;
                float4 p0 = *(const float4*)p;
                float4 p1 = *(const float4*)(p + 4);
                h8v av = {(_Float16)p0.x, (_Float16)p0.y, (_Float16)p0.z, (_Float16)p0.w,
                          (_Float16)p1.x, (_Float16)p1.y, (_Float16)p1.z, (_Float16)p1.w};
                a[m] = av;
            }
#pragma unroll
            for (int m = 0; m < 2; m++)
#pragma unroll
                for (int t = 0; t < 2; t++) {
                    acc[m][t] = __builtin_amdgcn_mfma_f32_16x16x32_f16(a[m], bh[c][t], acc[m][t], 0, 0, 0);
                    acc[m][t] = __builtin_amdgcn_mfma_f32_16x16x32_f16(a[m], bl[c][t], acc[m][t], 0, 0, 0);
                }
        }
#pragma unroll
        for (int m = 0; m < 2; m++)
#pragma unroll
            for (int reg = 0; reg < 4; reg++) {
                int r = r0 + m * 16 + quad * 4 + reg;
                float dv = dinv[r];
#pragma unroll
                for (int t = 0; t < 2; t++)
                    out[(size_t)r * 128 + nb + t * 16 + nn] = (_Float16)(acc[m][t][reg] * dv);
            }
    }
}

__launch_bounds__(256, 2)
__global__ void k_gemm128(const _Float16* __restrict__ A,
                          const _Float16* __restrict__ Wthi, const _Float16* __restrict__ Wtlo,
                          const float* __restrict__ dinv, _Float16* __restrict__ out) {
    const int lane = threadIdx.x & 63;
    const int wi = threadIdx.x >> 6;
    const int nb = wi * 32;
    const int nn = lane & 15;
    const int kq = (lane >> 4) * 8;
    const int quad = lane >> 4;

    h8v bh[4][2], bl[4][2];
#pragma unroll
    for (int c = 0; c < 4; c++)
#pragma unroll
        for (int t = 0; t < 2; t++) {
            int off = (nb + t * 16 + nn) * 128 + c * 32 + kq;
            bh[c][t] = *(const h8v*)(Wthi + off);
            bl[c][t] = *(const h8v*)(Wtlo + off);
        }

    for (int rt = blockIdx.x; rt < NTILES; rt += GEMM_GRID) {
        const int r0 = rt * 32;
        f32x4 acc[2][2] = {};
#pragma unroll
        for (int c = 0; c < 4; c++) {
            h8v a[2];
#pragma unroll
            for (int m = 0; m < 2; m++)
                a[m] = *(const h8v*)(A + (size_t)(r0 + m * 16 + nn) * 128 + c * 32 + kq);
#pragma unroll
            for (int m = 0; m < 2; m++)
#pragma unroll
                for (int t = 0; t < 2; t++) {
                    acc[m][t] = __builtin_amdgcn_mfma_f32_16x16x32_f16(a[m], bh[c][t], acc[m][t], 0, 0, 0);
                    acc[m][t] = __builtin_amdgcn_mfma_f32_16x16x32_f16(a[m], bl[c][t], acc[m][t], 0, 0, 0);
                }
        }
#pragma unroll
        for (int m = 0; m < 2; m++)
#pragma unroll
            for (int reg = 0; reg < 4; reg++) {
                int r = r0 + m * 16 + quad * 4 + reg;
                float dv = dinv[r];
#pragma unroll
                for (int t = 0; t < 2; t++)
                    out[(size_t)r * 128 + nb + t * 16 + nn] = (_Float16)(acc[m][t][reg] * dv);
            }
    }
}

// Layer-3 GEMM: 40 real cols (48 written) into [N+1][64]-stride buffer.
// Persistent B (24 fragments); wave-level grid-stride over tiles.
#define G40_GRID 160

__launch_bounds__(256, 2)
__global__ void k_gemm40(const _Float16* __restrict__ A,
                         const _Float16* __restrict__ Wthi, const _Float16* __restrict__ Wtlo,
                         const float* __restrict__ dinv, _Float16* __restrict__ out) {
    const int lane = threadIdx.x & 63;
    const int wi = threadIdx.x >> 6;
    const int nn = lane & 15;
    const int kq = (lane >> 4) * 8;
    const int quad = lane >> 4;

    h8v bh[4][3], bl[4][3];
#pragma unroll
    for (int c = 0; c < 4; c++)
#pragma unroll
        for (int t = 0; t < 3; t++) {
            int off = (t * 16 + nn) * 128 + c * 32 + kq;
            bh[c][t] = *(const h8v*)(Wthi + off);
            bl[c][t] = *(const h8v*)(Wtlo + off);
        }

    for (int rt = blockIdx.x * 4 + wi; rt < NTILES; rt += G40_GRID * 4) {
        const int r0 = rt * 32;
        f32x4 acc[2][3] = {};
#pragma unroll
        for (int c = 0; c < 4; c++) {
            h8v a[2];
#pragma unroll
            for (int m = 0; m < 2; m++)
                a[m] = *(const h8v*)(A + (size_t)(r0 + m * 16 + nn) * 128 + c * 32 + kq);
#pragma unroll
            for (int m = 0; m < 2; m++)
#pragma unroll
                for (int t = 0; t < 3; t++) {
                    acc[m][t] = __builtin_amdgcn_mfma_f32_16x16x32_f16(a[m], bh[c][t], acc[m][t], 0, 0, 0);
                    acc[m][t] = __builtin_amdgcn_mfma_f32_16x16x32_f16(a[m], bl[c][t], acc[m][t], 0, 0, 0);
                }
        }
#pragma unroll
        for (int m = 0; m < 2; m++)
#pragma unroll
            for (int reg = 0; reg < 4; reg++) {
                int r = r0 + m * 16 + quad * 4 + reg;
                float dv = dinv[r];
#pragma unroll
                for (int t = 0; t < 3; t++)
                    out[(size_t)r * 64 + t * 16 + nn] = (_Float16)(acc[m][t][reg] * dv);
            }
    }
}

// ---------------- Slot-parallel aggregation (F=128) ----------------

__launch_bounds__(256)
__global__ void k_agg4(const _Float16* __restrict__ hp, const int2* __restrict__ rowse,
                       const int* __restrict__ colidx, const float* __restrict__ bias,
                       _Float16* __restrict__ outp) {
    const int lane = threadIdx.x & 63;
    const int wid = (blockIdx.x * blockDim.x + threadIdx.x) >> 6;
    const int rs = lane >> 4;   // row slot 0..3
    const int cp = lane & 15;   // 16B col part
    const int r = wid * 4 + rs;

    const int2 se = rowse[r];
    const int deg = se.y - se.x;
    int m = deg;
    m = max(m, __shfl_xor(m, 16));
    m = max(m, __shfl_xor(m, 32));

    const _Float16* hpc = hp + cp * 8;
    h8v acc = {};
    for (int it = 0; it < m; it += 4) {
        int i0 = se.x + it;
        int s0 = colidx[i0];
        int s1 = colidx[i0 + 1];
        int s2 = colidx[i0 + 2];
        int s3 = colidx[i0 + 3];
        s0 = (it < deg) ? s0 : N_NODES;
        s1 = (it + 1 < deg) ? s1 : N_NODES;
        s2 = (it + 2 < deg) ? s2 : N_NODES;
        s3 = (it + 3 < deg) ? s3 : N_NODES;
        h8v v0 = *(const h8v*)(hpc + (size_t)s0 * 128);
        h8v v1 = *(const h8v*)(hpc + (size_t)s1 * 128);
        h8v v2 = *(const h8v*)(hpc + (size_t)s2 * 128);
        h8v v3 = *(const h8v*)(hpc + (size_t)s3 * 128);
        acc += v0;
        acc += v1;
        acc += v2;
        acc += v3;
    }

    h8v sv = *(const h8v*)(hpc + (size_t)r * 128);  // self-loop
    float dv = rsqrtf((float)(deg + 1));
    const float* bp = bias + cp * 8;
    float4 b0 = *(const float4*)bp;
    float4 b1 = *(const float4*)(bp + 4);
    float bb[8] = {b0.x, b0.y, b0.z, b0.w, b1.x, b1.y, b1.z, b1.w};
    h8v o;
#pragma unroll
    for (int j = 0; j < 8; j++) {
        float s = (float)acc[j] + (float)sv[j];
        o[j] = (_Float16)fmaxf(fmaf(dv, s, bb[j]), 0.f);
    }
    *(h8v*)(outp + (size_t)r * 128 + cp * 8) = o;
}

// ---------------- Final aggregation (64-stride rows) + fused log_softmax ----------------

__launch_bounds__(256)
__global__ void k_agg_out(const _Float16* __restrict__ hp, const int2* __restrict__ rowse,
                          const int* __restrict__ colidx, float* __restrict__ out) {
    const int lane = threadIdx.x & 63;
    const int wid = (blockIdx.x * blockDim.x + threadIdx.x) >> 6;
    const int rs = lane >> 3;   // row slot 0..7
    const int cp = lane & 7;    // 16B col part
    const int r = wid * 8 + rs;

    const int2 se = rowse[r];
    const int deg = se.y - se.x;
    int m = deg;
    m = max(m, __shfl_xor(m, 8));
    m = max(m, __shfl_xor(m, 16));
    m = max(m, __shfl_xor(m, 32));

    const _Float16* hpc = hp + cp * 8;
    h8v acc = {};
    for (int it = 0; it < m; it += 4) {
        int i0 = se.x + it;
        int s0 = colidx[i0];
        int s1 = colidx[i0 + 1];
        int s2 = colidx[i0 + 2];
        int s3 = colidx[i0 + 3];
        s0 = (it < deg) ? s0 : N_NODES;
        s1 = (it + 1 < deg) ? s1 : N_NODES;
        s2 = (it + 2 < deg) ? s2 : N_NODES;
        s3 = (it + 3 < deg) ? s3 : N_NODES;
        h8v v0 = *(const h8v*)(hpc + (size_t)s0 * 64);
        h8v v1 = *(const h8v*)(hpc + (size_t)s1 * 64);
        h8v v2 = *(const h8v*)(hpc + (size_t)s2 * 64);
        h8v v3 = *(const h8v*)(hpc + (size_t)s3 * 64);
        acc += v0;
        acc += v1;
        acc += v2;
        acc += v3;
    }

    h8v sv = *(const h8v*)(hpc + (size_t)r * 64);  // self-loop
    float dv = rsqrtf((float)(deg + 1));
    float z[8];
#pragma unroll
    for (int j = 0; j < 8; j++) z[j] = dv * ((float)acc[j] + (float)sv[j]);

    const bool act = cp < 5;  // cols 0..39
    float pm = -INFINITY;
    if (act) {
#pragma unroll
        for (int j = 0; j < 8; j++) pm = fmaxf(pm, z[j]);
    }
    pm = fmaxf(pm, __shfl_xor(pm, 1));
    pm = fmaxf(pm, __shfl_xor(pm, 2));
    pm = fmaxf(pm, __shfl_xor(pm, 4));
    float pe = 0.f;
    if (act) {
#pragma unroll
        for (int j = 0; j < 8; j++) pe += __expf(z[j] - pm);
    }
    pe += __shfl_xor(pe, 1);
    pe += __shfl_xor(pe, 2);
    pe += __shfl_xor(pe, 4);
    float lse = __logf(pe);
    if (act) {
        float* po = out + (size_t)r * 40 + cp * 8;
        float4 o0 = make_float4(z[0] - pm - lse, z[1] - pm - lse, z[2] - pm - lse, z[3] - pm - lse);
        float4 o1 = make_float4(z[4] - pm - lse, z[5] - pm - lse, z[6] - pm - lse, z[7] - pm - lse);
        *(float4*)po = o0;
        *(float4*)(po + 4) = o1;
    }
}

// ---------------- launch ----------------

extern "C" void kernel_launch(void* const* d_in, const int* in_sizes, int n_in,
                              void* d_out, int out_size, void* d_ws, size_t ws_size,
                              hipStream_t stream) {
    const float* x     = (const float*)d_in[0];
    const int*   ei    = (const int*)d_in[1];
    const float* W_in  = (const float*)d_in[2];
    const float* b_in  = (const float*)d_in[3];
    const float* W_mid = (const float*)d_in[4];
    const float* b_mid = (const float*)d_in[5];
    const float* W_out = (const float*)d_in[6];
    float* out = (float*)d_out;

    const int* srcv = ei;
    const int* dstv = ei + N_EDGES;

    char* w = (char*)d_ws;
    float* dinv   = (float*)(w);                              // 400 KB
    int2* rowse   = (int2*)(w + (1ull << 19));                // 800 KB
    int* bcnt     = (int*)(w + 1507328);                      // 2 KB
    int* colidx   = (int*)(w + (2ull << 20));                 // 7.2 MB + pad
    unsigned int* ebuf = (unsigned int*)(w + (10ull << 20));  // 7.2 MB
    _Float16* Wt  = (_Float16*)(w + (18ull << 20));           // 155 KB
    _Float16* bufA = (_Float16*)(w + (19ull << 20));          // (N+1)*128 fp16
    _Float16* bufB = (_Float16*)(w + (45ull << 20));          // (N+1)*128 fp16
    _Float16* zbuf = (_Float16*)(w + (71ull << 20));          // (N+1)*64 fp16

    _Float16* W1h = Wt;
    _Float16* W1l = Wt + 128 * 128;
    _Float16* W2h = Wt + 2 * 128 * 128;
    _Float16* W2l = Wt + 3 * 128 * 128;
    _Float16* W3h = Wt + 4 * 128 * 128;
    _Float16* W3l = Wt + 4 * 128 * 128 + 48 * 128;

    const int NB_PART = (N_EDGES + 4095) / 4096;  // 391

    // CSR build
    hipMemsetAsync(bcnt, 0, NBUCK * sizeof(int), stream);
    k_zrows<<<1, 256, 0, stream>>>(bufA, zbuf);
    k_bpart<<<NB_PART, 256, 0, stream>>>(srcv, dstv, bcnt, ebuf);
    k_bucket<<<NBUCK, 256, 0, stream>>>(ebuf, bcnt, rowse, dinv, colidx);

    // weight prep (one launch)
    k_wprep_all<<<(304 * 128 + 255) / 256, 256, 0, stream>>>(W_in, W_mid, W_out, Wt);

    const int AGG4_BLOCKS = N_NODES / 16;   // 6250
    const int AGGO_BLOCKS = N_NODES / 32;   // 3125

    // Layer 1 (reads fp32 x directly)
    k_gemm128_f32<<<GEMM_GRID, 256, 0, stream>>>(x, W1h, W1l, dinv, bufA);
    k_agg4<<<AGG4_BLOCKS, 256, 0, stream>>>(bufA, rowse, colidx, b_in, bufB);
    // Layer 2
    k_gemm128<<<GEMM_GRID, 256, 0, stream>>>(bufB, W2h, W2l, dinv, bufA);
    k_agg4<<<AGG4_BLOCKS, 256, 0, stream>>>(bufA, rowse, colidx, b_mid, bufB);
    // Layer 3 + fused log_softmax
    k_gemm40<<<G40_GRID, 256, 0, stream>>>(bufB, W3h, W3l, dinv, zbuf);
    k_agg_out<<<AGGO_BLOCKS, 256, 0, stream>>>(zbuf, rowse, colidx, out);
}